// Round 19
// baseline (276.951 us; speedup 1.0000x reference)
//
#include <hip/hip_runtime.h>

#define NN 100000
#define NE 1600000
#define NBUCK 391          // buckets of 256 nodes
#define CAP 5632           // per-bucket capacity (mean 4096, +24 sigma)

typedef __attribute__((ext_vector_type(8))) short bf16x8;
typedef __attribute__((ext_vector_type(4))) short bf16x4;
typedef __attribute__((ext_vector_type(4))) float f32x4;

__device__ inline unsigned short f2bf(float f) {
    unsigned int u = __float_as_uint(f);
    return (unsigned short)((u + 0x7FFFu + ((u >> 16) & 1u)) >> 16);   // RNE bf16
}
__device__ inline float bf2f(short s) {
    return __uint_as_float(((unsigned int)(unsigned short)s) << 16);
}

// ---- phase 1: bin edges into 391 node-range buckets (LDS histogram) ----
__global__ __launch_bounds__(256) void k_bin(const int* __restrict__ row, const int* __restrict__ col,
                                             int* __restrict__ gcursor, int* __restrict__ ebuf) {
    __shared__ int hist[NBUCK];
    for (int i = threadIdx.x; i < NBUCK; i += 256) hist[i] = 0;
    __syncthreads();
    int start = blockIdx.x * 3125;
    int end = start + 3125; if (end > NE) end = NE;
    for (int e = start + threadIdx.x; e < end; e += 256)
        atomicAdd(&hist[row[e] >> 8], 1);
    __syncthreads();
    for (int i = threadIdx.x; i < NBUCK; i += 256)
        hist[i] = atomicAdd(&gcursor[i], hist[i]);
    __syncthreads();
    for (int e = start + threadIdx.x; e < end; e += 256) {
        int r = row[e], c = col[e];
        int bk = r >> 8;
        int pos = atomicAdd(&hist[bk], 1);
        if (pos < CAP) ebuf[bk * CAP + pos] = (c << 8) | (r & 255);
    }
}

// ---- phase 2: per-bucket CSR build; bucket-scan folded in (each block
//      redundantly scans the 391 counts in LDS - cheap, saves a launch) ----
__global__ __launch_bounds__(256) void k_build(const int* __restrict__ ebuf, const int* __restrict__ gcursor,
                                               int* __restrict__ row_ptr, float* __restrict__ dinv,
                                               float* __restrict__ rdeg, int* __restrict__ col_sorted) {
    __shared__ int deg[256], cur[256], ps[256];
    __shared__ int bsL[NBUCK + 1];
    int t = threadIdx.x;
    // exclusive scan of bucket counts (2 elems/thread)
    int d0 = (2 * t < NBUCK) ? gcursor[2 * t] : 0;
    int d1 = (2 * t + 1 < NBUCK) ? gcursor[2 * t + 1] : 0;
    ps[t] = d0 + d1;
    __syncthreads();
    for (int off = 1; off < 256; off <<= 1) {
        int v = (t >= off) ? ps[t - off] : 0;
        __syncthreads();
        ps[t] += v;
        __syncthreads();
    }
    int ex = ps[t] - d0 - d1;
    if (2 * t < NBUCK) bsL[2 * t] = ex;
    if (2 * t + 1 < NBUCK) bsL[2 * t + 1] = ex + d0;
    __syncthreads();
    int b = blockIdx.x;
    int bs = bsL[b];
    int cnt = gcursor[b];
    const int* eb = ebuf + (size_t)b * CAP;
    deg[t] = 0;
    __syncthreads();
    for (int e = t; e < cnt; e += 256)
        atomicAdd(&deg[eb[e] & 255], 1);
    __syncthreads();
    int d = deg[t];
    ps[t] = d; __syncthreads();
    for (int off = 1; off < 256; off <<= 1) {
        int v = (t >= off) ? ps[t - off] : 0;
        __syncthreads();
        ps[t] += v;
        __syncthreads();
    }
    int base = bs + ps[t] - d;
    cur[t] = base;
    int n = (b << 8) + t;
    if (n < NN) {
        row_ptr[n] = base;
        dinv[n] = d > 0 ? rsqrtf((float)d) : 0.f;
        rdeg[n] = sqrtf((float)d);
    }
    if (b == 0 && t == 0) row_ptr[NN] = NE;
    __syncthreads();
    for (int e = t; e < cnt; e += 256) {
        int w = eb[e];
        int pos = atomicAdd(&cur[w & 255], 1);
        col_sorted[pos] = ((unsigned)w) >> 8;
    }
}

// ---- bf16 copies: xbf = bf16(x), xsbf = bf16(x*dinv) ----
__global__ void k_scale(const float* __restrict__ x, const float* __restrict__ dinv,
                        unsigned short* __restrict__ xsbf, unsigned short* __restrict__ xbf) {
    int t = blockIdx.x * 256 + threadIdx.x;
    if (t < NN * 16) {
        float d = dinv[t >> 4];
        f32x4 v = ((const f32x4*)x)[t];
        bf16x4 u, s;
        u[0] = (short)f2bf(v[0]); u[1] = (short)f2bf(v[1]); u[2] = (short)f2bf(v[2]); u[3] = (short)f2bf(v[3]);
        s[0] = (short)f2bf(v[0] * d); s[1] = (short)f2bf(v[1] * d); s[2] = (short)f2bf(v[2] * d); s[3] = (short)f2bf(v[3] * d);
        ((bf16x4*)xbf)[t] = u;
        ((bf16x4*)xsbf)[t] = s;
    }
}

// ---- 64-wide bf16 SpMM pass 1: T1s = dinv * (-dinv*sum) only ----
__global__ __launch_bounds__(256) void k_spmm64b(const unsigned short* __restrict__ ins,
                                                 unsigned short* __restrict__ outsb,
                                                 const int* __restrict__ row_ptr, const int* __restrict__ cs,
                                                 const float* __restrict__ dinv) {
    int n = blockIdx.x * 4 + (threadIdx.x >> 6);
    if (n >= NN) return;
    int nu = __builtin_amdgcn_readfirstlane(n);
    int lane = threadIdx.x & 63;
    int es = lane >> 3;     // edge slot 0..7
    int f = lane & 7;       // features 8f..8f+7 (16 B)
    int s = row_ptr[nu], e = row_ptr[nu + 1];
    float a0[8] = {0,0,0,0,0,0,0,0}, a1[8] = {0,0,0,0,0,0,0,0};
    int i = s;
    for (; i + 15 < e; i += 16) {
        int c0 = cs[i + es];
        int c1 = cs[i + 8 + es];
        bf16x8 v0 = *((const bf16x8*)(ins + (size_t)c0 * 64 + f * 8));
        bf16x8 v1 = *((const bf16x8*)(ins + (size_t)c1 * 64 + f * 8));
        #pragma unroll
        for (int j = 0; j < 8; ++j) { a0[j] += bf2f(v0[j]); a1[j] += bf2f(v1[j]); }
    }
    for (; i + es < e; i += 8) {
        int c0 = cs[i + es];
        bf16x8 v0 = *((const bf16x8*)(ins + (size_t)c0 * 64 + f * 8));
        #pragma unroll
        for (int j = 0; j < 8; ++j) a0[j] += bf2f(v0[j]);
    }
    float a[8];
    #pragma unroll
    for (int j = 0; j < 8; ++j) {
        a[j] = a0[j] + a1[j];
        a[j] += __shfl_xor(a[j], 8);
        a[j] += __shfl_xor(a[j], 16);
        a[j] += __shfl_xor(a[j], 32);
    }
    if (es == 0) {
        float dn = dinv[nu];
        bf16x8 os;
        #pragma unroll
        for (int j = 0; j < 8; ++j) os[j] = (short)f2bf(dn * (-dn * a[j]));
        *((bf16x8*)(outsb + (size_t)nu * 64 + f * 8)) = os;
    }
}

// ---- FUSED: pass-2 gather (T2 to LDS only) + dense1 + proj.
//      Block = 16-node tile. Gather: wave w -> nodes w*4..w*4+3.
//      Phase A: wave w computes h[:,16w:16w+16] (T1 term via rd*(T1s@W)).
//      Phase B: waves 0-2 compute Apre / Gs-lo / Gs-hi. T2 never hits HBM. ----
__global__ __launch_bounds__(256) void k_fuse(const unsigned short* __restrict__ xbf,
                                              const unsigned short* __restrict__ t1s,
                                              const float* __restrict__ W1, const float* __restrict__ b1,
                                              const float* __restrict__ W2, const float* __restrict__ b2,
                                              const float* __restrict__ dinv, const float* __restrict__ rdeg,
                                              const int* __restrict__ row_ptr, const int* __restrict__ cs,
                                              unsigned short* __restrict__ Apreb, unsigned short* __restrict__ Gsb) {
    __shared__ unsigned short Wf1[24 * 64 * 8];   // 24576 B
    __shared__ unsigned short Wf2[6 * 64 * 8];    //  3072 B
    __shared__ unsigned short T2t[16 * 64];       //  2048 B (swizzled)
    __shared__ unsigned short Htile[16 * 64];     //  2048 B (swizzled)
    for (int slot = threadIdx.x; slot < 24 * 64; slot += 256) {
        int c = slot / 384;
        int t = (slot / 64) % 6;
        int l = slot & 63;
        int rr = l & 15, gg = l >> 4;
        unsigned int pk[4];
        #pragma unroll
        for (int jp = 0; jp < 4; ++jp) {
            int k0 = t * 32 + gg * 8 + jp * 2;
            unsigned int lo = f2bf(W1[(k0 >> 6) * 4096 + (k0 & 63) * 64 + c * 16 + rr]);
            int k1 = k0 + 1;
            unsigned int hi = f2bf(W1[(k1 >> 6) * 4096 + (k1 & 63) * 64 + c * 16 + rr]);
            pk[jp] = lo | (hi << 16);
        }
        *((uint4*)&Wf1[slot * 8]) = *((uint4*)pk);
    }
    for (int slot = threadIdx.x; slot < 6 * 64; slot += 256) {
        int c = slot / 128;
        int t = (slot / 64) & 1;
        int l = slot & 63;
        int rr = l & 15, gg = l >> 4;
        unsigned int pk[4];
        #pragma unroll
        for (int jp = 0; jp < 4; ++jp) {
            int k0 = t * 32 + gg * 8 + jp * 2;
            int k1 = k0 + 1;
            float w0, w1;
            if (c == 0)      { w0 = W2[k0 * 16 + rr] - W2[2048 + k0 * 16 + rr];
                               w1 = W2[k1 * 16 + rr] - W2[2048 + k1 * 16 + rr]; }
            else if (c == 1) { w0 = W2[1024 + k0 * 16 + rr]; w1 = W2[1024 + k1 * 16 + rr]; }
            else             { w0 = W2[2048 + k0 * 16 + rr]; w1 = W2[2048 + k1 * 16 + rr]; }
            pk[jp] = (unsigned int)f2bf(w0) | ((unsigned int)f2bf(w1) << 16);
        }
        *((uint4*)&Wf2[slot * 8]) = *((uint4*)pk);
    }

    int lane = threadIdx.x & 63;
    int widx = threadIdx.x >> 6;
    int r = lane & 15, g = lane >> 4;
    int nb = blockIdx.x * 16;

    // ---- gather phase: 4 nodes per wave, 8-edge MLP each ----
    int es = lane >> 3, fq = lane & 7;
    #pragma unroll
    for (int q = 0; q < 4; ++q) {
        int n = nb + widx * 4 + q;
        int s = row_ptr[n], e = row_ptr[n + 1];
        float a0[8] = {0,0,0,0,0,0,0,0}, a1[8] = {0,0,0,0,0,0,0,0};
        int i = s;
        for (; i + 15 < e; i += 16) {
            int c0 = cs[i + es];
            int c1 = cs[i + 8 + es];
            bf16x8 v0 = *((const bf16x8*)(t1s + (size_t)c0 * 64 + fq * 8));
            bf16x8 v1 = *((const bf16x8*)(t1s + (size_t)c1 * 64 + fq * 8));
            #pragma unroll
            for (int j = 0; j < 8; ++j) { a0[j] += bf2f(v0[j]); a1[j] += bf2f(v1[j]); }
        }
        for (; i + es < e; i += 8) {
            int c0 = cs[i + es];
            bf16x8 v0 = *((const bf16x8*)(t1s + (size_t)c0 * 64 + fq * 8));
            #pragma unroll
            for (int j = 0; j < 8; ++j) a0[j] += bf2f(v0[j]);
        }
        float a[8];
        #pragma unroll
        for (int j = 0; j < 8; ++j) {
            a[j] = a0[j] + a1[j];
            a[j] += __shfl_xor(a[j], 8);
            a[j] += __shfl_xor(a[j], 16);
            a[j] += __shfl_xor(a[j], 32);
        }
        if (es == 0) {
            float dn = dinv[n];
            bf16x8 xv = *((const bf16x8*)(xbf + (size_t)n * 64 + fq * 8));
            bf16x8 ob;
            #pragma unroll
            for (int j = 0; j < 8; ++j)
                ob[j] = (short)f2bf(2.f * (-dn * a[j]) - bf2f(xv[j]));
            int ln = widx * 4 + q;
            int byte = (ln * 128 + fq * 16) ^ ((ln & 7) << 4);
            *((bf16x8*)((char*)T2t + byte)) = ob;
        }
    }
    __syncthreads();

    // ---- phase A: this wave's h column-slice c = widx ----
    bf16x8 bfr1[6];
    #pragma unroll
    for (int t = 0; t < 6; ++t)
        bfr1[t] = *((const bf16x8*)&Wf1[((widx * 6 + t) * 64 + lane) * 8]);
    float bl = b1[widx * 16 + r];

    bf16x8 af[6];
    af[0] = *((const bf16x8*)(xbf + (size_t)(nb + r) * 64 + g * 8));
    af[1] = *((const bf16x8*)(xbf + (size_t)(nb + r) * 64 + 32 + g * 8));
    af[2] = *((const bf16x8*)(t1s + (size_t)(nb + r) * 64 + g * 8));
    af[3] = *((const bf16x8*)(t1s + (size_t)(nb + r) * 64 + 32 + g * 8));
    {
        int byte0 = (r * 128 + g * 16) ^ ((r & 7) << 4);
        int byte1 = (r * 128 + 64 + g * 16) ^ ((r & 7) << 4);
        af[4] = *((const bf16x8*)((char*)T2t + byte0));
        af[5] = *((const bf16x8*)((char*)T2t + byte1));
    }
    f32x4 acc = (f32x4){bl, bl, bl, bl};
    f32x4 accT = (f32x4){0.f, 0.f, 0.f, 0.f};
    acc  = __builtin_amdgcn_mfma_f32_16x16x32_bf16(af[0], bfr1[0], acc, 0, 0, 0);
    acc  = __builtin_amdgcn_mfma_f32_16x16x32_bf16(af[1], bfr1[1], acc, 0, 0, 0);
    accT = __builtin_amdgcn_mfma_f32_16x16x32_bf16(af[2], bfr1[2], accT, 0, 0, 0);
    accT = __builtin_amdgcn_mfma_f32_16x16x32_bf16(af[3], bfr1[3], accT, 0, 0, 0);
    acc  = __builtin_amdgcn_mfma_f32_16x16x32_bf16(af[4], bfr1[4], acc, 0, 0, 0);
    acc  = __builtin_amdgcn_mfma_f32_16x16x32_bf16(af[5], bfr1[5], acc, 0, 0, 0);
    #pragma unroll
    for (int q = 0; q < 4; ++q) {
        int node = g * 4 + q;
        float hval = fmaxf(acc[q] + rdeg[nb + node] * accT[q], 0.f);
        int byte = (node * 128 + (widx * 16 + r) * 2) ^ ((node & 7) << 4);
        *((unsigned short*)((char*)Htile + byte)) = f2bf(hval);
    }
    __syncthreads();

    // ---- phase B: waves 0-2 compute proj slices ----
    if (widx < 3) {
        bf16x8 bfr2[2];
        #pragma unroll
        for (int t = 0; t < 2; ++t)
            bfr2[t] = *((const bf16x8*)&Wf2[((widx * 2 + t) * 64 + lane) * 8]);
        bf16x8 af2[2];
        {
            int byte0 = (r * 128 + g * 16) ^ ((r & 7) << 4);
            int byte1 = (r * 128 + 64 + g * 16) ^ ((r & 7) << 4);
            af2[0] = *((const bf16x8*)((char*)Htile + byte0));
            af2[1] = *((const bf16x8*)((char*)Htile + byte1));
        }
        f32x4 acc2 = (f32x4){0.f, 0.f, 0.f, 0.f};
        acc2 = __builtin_amdgcn_mfma_f32_16x16x32_bf16(af2[0], bfr2[0], acc2, 0, 0, 0);
        acc2 = __builtin_amdgcn_mfma_f32_16x16x32_bf16(af2[1], bfr2[1], acc2, 0, 0, 0);
        float b2r = b2[r];
        #pragma unroll
        for (int q = 0; q < 4; ++q) {
            int n = nb + g * 4 + q;
            if (widx == 0)      Apreb[(size_t)n * 16 + r] = f2bf(acc2[q] + b2r);
            else if (widx == 1) Gsb[(size_t)n * 32 + r]      = f2bf(acc2[q] * dinv[n]);
            else                Gsb[(size_t)n * 32 + 16 + r] = f2bf(acc2[q] * dinv[n]);
        }
    }
}

// ---- 32-wide bf16 SpMM: q1b = bf16(P(g1)); ts = bf16(dinv*P(g2)) ----
__global__ __launch_bounds__(256) void k_spmm32b(const unsigned short* __restrict__ Gsb,
                                                 unsigned short* __restrict__ q1b, unsigned short* __restrict__ tsb,
                                                 const int* __restrict__ row_ptr, const int* __restrict__ cs,
                                                 const float* __restrict__ dinv) {
    int n = blockIdx.x * 4 + (threadIdx.x >> 6);
    if (n >= NN) return;
    int nu = __builtin_amdgcn_readfirstlane(n);
    int lane = threadIdx.x & 63;
    int es = lane >> 3;
    int f = lane & 7;
    int s = row_ptr[nu], e = row_ptr[nu + 1];
    float a0[4] = {0,0,0,0}, a1[4] = {0,0,0,0};
    int i = s;
    for (; i + 15 < e; i += 16) {
        int c0 = cs[i + es];
        int c1 = cs[i + 8 + es];
        bf16x4 v0 = *((const bf16x4*)(Gsb + (size_t)c0 * 32 + f * 4));
        bf16x4 v1 = *((const bf16x4*)(Gsb + (size_t)c1 * 32 + f * 4));
        #pragma unroll
        for (int j = 0; j < 4; ++j) { a0[j] += bf2f(v0[j]); a1[j] += bf2f(v1[j]); }
    }
    for (; i + es < e; i += 8) {
        int c0 = cs[i + es];
        bf16x4 v0 = *((const bf16x4*)(Gsb + (size_t)c0 * 32 + f * 4));
        #pragma unroll
        for (int j = 0; j < 4; ++j) a0[j] += bf2f(v0[j]);
    }
    float a[4];
    #pragma unroll
    for (int j = 0; j < 4; ++j) {
        a[j] = a0[j] + a1[j];
        a[j] += __shfl_xor(a[j], 8);
        a[j] += __shfl_xor(a[j], 16);
        a[j] += __shfl_xor(a[j], 32);
    }
    if (es == 0) {
        float dn = dinv[nu];
        if (f < 4) {
            bf16x4 w;
            #pragma unroll
            for (int j = 0; j < 4; ++j) w[j] = (short)f2bf(-dn * a[j]);
            *((bf16x4*)(q1b + (size_t)nu * 16 + f * 4)) = w;
        } else {
            bf16x4 w;
            #pragma unroll
            for (int j = 0; j < 4; ++j) w[j] = (short)f2bf(dn * (-dn * a[j]));
            *((bf16x4*)(tsb + (size_t)nu * 16 + (f - 4) * 4)) = w;
        }
    }
}

// ---- 16-wide bf16 SpMM + combine + log_softmax ----
__global__ __launch_bounds__(256) void k_spmm16f(const unsigned short* __restrict__ tsb,
                                                 const unsigned short* __restrict__ Apreb,
                                                 const unsigned short* __restrict__ q1b,
                                                 const int* __restrict__ row_ptr, const int* __restrict__ cs,
                                                 const float* __restrict__ dinv, float* __restrict__ out) {
    int n = blockIdx.x * 4 + (threadIdx.x >> 6);
    if (n >= NN) return;
    int nu = __builtin_amdgcn_readfirstlane(n);
    int lane = threadIdx.x & 63;
    int es = lane >> 2;
    int f = lane & 3;
    int s = row_ptr[nu], e = row_ptr[nu + 1];
    float a0[4] = {0,0,0,0}, a1[4] = {0,0,0,0};
    int i = s;
    for (; i + 31 < e; i += 32) {
        int c0 = cs[i + es];
        int c1 = cs[i + 16 + es];
        bf16x4 v0 = *((const bf16x4*)(tsb + (size_t)c0 * 16 + f * 4));
        bf16x4 v1 = *((const bf16x4*)(tsb + (size_t)c1 * 16 + f * 4));
        #pragma unroll
        for (int j = 0; j < 4; ++j) { a0[j] += bf2f(v0[j]); a1[j] += bf2f(v1[j]); }
    }
    for (; i + es < e; i += 16) {
        int c0 = cs[i + es];
        bf16x4 v0 = *((const bf16x4*)(tsb + (size_t)c0 * 16 + f * 4));
        #pragma unroll
        for (int j = 0; j < 4; ++j) a0[j] += bf2f(v0[j]);
    }
    float a[4];
    #pragma unroll
    for (int j = 0; j < 4; ++j) {
        a[j] = a0[j] + a1[j];
        a[j] += __shfl_xor(a[j], 4);
        a[j] += __shfl_xor(a[j], 8);
        a[j] += __shfl_xor(a[j], 16);
        a[j] += __shfl_xor(a[j], 32);
    }
    if (es == 0) {
        float dn = dinv[nu];
        bf16x4 ap = *((const bf16x4*)(Apreb + (size_t)nu * 16 + f * 4));
        bf16x4 qv = *((const bf16x4*)(q1b + (size_t)nu * 16 + f * 4));
        float o[4];
        #pragma unroll
        for (int j = 0; j < 4; ++j)
            o[j] = bf2f(ap[j]) + bf2f(qv[j]) + 2.f * (-dn * a[j]);
        float m = fmaxf(fmaxf(o[0], o[1]), fmaxf(o[2], o[3]));
        m = fmaxf(m, __shfl_xor(m, 1));
        m = fmaxf(m, __shfl_xor(m, 2));
        float ssum = expf(o[0] - m) + expf(o[1] - m) + expf(o[2] - m) + expf(o[3] - m);
        ssum += __shfl_xor(ssum, 1);
        ssum += __shfl_xor(ssum, 2);
        float ls = logf(ssum);
        f32x4 w;
        w[0] = o[0] - m - ls; w[1] = o[1] - m - ls; w[2] = o[2] - m - ls; w[3] = o[3] - m - ls;
        *((f32x4*)(out + (size_t)nu * 16 + f * 4)) = w;
    }
}

extern "C" void kernel_launch(void* const* d_in, const int* in_sizes, int n_in,
                              void* d_out, int out_size, void* d_ws, size_t ws_size,
                              hipStream_t stream) {
    const float* x  = (const float*)d_in[0];
    const int*   ei = (const int*)d_in[1];
    const int*   row = ei;
    const int*   col = ei + NE;
    const float* W1 = (const float*)d_in[2];
    const float* b1 = (const float*)d_in[3];
    const float* W2 = (const float*)d_in[4];
    const float* b2 = (const float*)d_in[5];
    float* out = (float*)d_out;

    char* base = (char*)d_ws;
    size_t off = 0;
    auto alloc = [&](size_t bytes) -> char* {
        char* r = base + off;
        off = (off + bytes + 255) & ~(size_t)255;
        return r;
    };
    int*   gcursor    = (int*)alloc(NBUCK * 4);
    float* dinv       = (float*)alloc((size_t)NN * 4);
    float* rdeg       = (float*)alloc((size_t)NN * 4);
    int*   row_ptr    = (int*)alloc((size_t)(NN + 1) * 4);
    int*   ebuf       = (int*)alloc((size_t)NBUCK * CAP * 4);
    int*   col_sorted = (int*)alloc((size_t)NE * 4);
    unsigned short* Xbf  = (unsigned short*)alloc((size_t)NN * 64 * 2);
    unsigned short* XSbf = (unsigned short*)alloc((size_t)NN * 64 * 2);
    unsigned short* T1s  = (unsigned short*)alloc((size_t)NN * 64 * 2);
    unsigned short* Apreb = (unsigned short*)alloc((size_t)NN * 16 * 2);
    unsigned short* Gsb  = (unsigned short*)alloc((size_t)NN * 32 * 2);
    unsigned short* q1b  = (unsigned short*)alloc((size_t)NN * 16 * 2);
    unsigned short* tsb  = (unsigned short*)alloc((size_t)NN * 16 * 2);

    hipMemsetAsync(gcursor, 0, NBUCK * 4, stream);

    // graph build (bstart folded into k_build)
    k_bin<<<512, 256, 0, stream>>>(row, col, gcursor, ebuf);
    k_build<<<NBUCK, 256, 0, stream>>>(ebuf, gcursor, row_ptr, dinv, rdeg, col_sorted);
    k_scale<<<(NN * 16 + 255) / 256, 256, 0, stream>>>(x, dinv, XSbf, Xbf);

    int nbS = (NN + 3) / 4;   // wave per node
    // layer-1 hop 1: T1s only
    k_spmm64b<<<nbS, 256, 0, stream>>>(XSbf, T1s, row_ptr, col_sorted, dinv);
    // fused: hop-2 gather (T2 in LDS) + dense1 + layer-2 projection
    k_fuse<<<NN / 16, 256, 0, stream>>>(Xbf, T1s, W1, b1, W2, b2, dinv, rdeg,
                                        row_ptr, col_sorted, Apreb, Gsb);
    // layer-2 narrow propagations
    k_spmm32b<<<nbS, 256, 0, stream>>>(Gsb, q1b, tsb, row_ptr, col_sorted, dinv);
    k_spmm16f<<<nbS, 256, 0, stream>>>(tsb, Apreb, q1b, row_ptr, col_sorted, dinv, out);
}

// Round 20
// 231.599 us; speedup vs baseline: 1.1958x; 1.1958x over previous
//
#include <hip/hip_runtime.h>

#define NN 100000
#define NE 1600000
#define NBUCK 391          // buckets of 256 nodes
#define CAP 5632           // per-bucket capacity (mean 4096, +24 sigma)

typedef __attribute__((ext_vector_type(8))) short bf16x8;
typedef __attribute__((ext_vector_type(4))) short bf16x4;
typedef __attribute__((ext_vector_type(4))) float f32x4;

__device__ inline unsigned short f2bf(float f) {
    unsigned int u = __float_as_uint(f);
    return (unsigned short)((u + 0x7FFFu + ((u >> 16) & 1u)) >> 16);   // RNE bf16
}
__device__ inline float bf2f(short s) {
    return __uint_as_float(((unsigned int)(unsigned short)s) << 16);
}

// ---- phase 1: bin edges into 391 node-range buckets (LDS histogram) ----
__global__ __launch_bounds__(256) void k_bin(const int* __restrict__ row, const int* __restrict__ col,
                                             int* __restrict__ gcursor, int* __restrict__ ebuf) {
    __shared__ int hist[NBUCK];
    for (int i = threadIdx.x; i < NBUCK; i += 256) hist[i] = 0;
    __syncthreads();
    int start = blockIdx.x * 3125;
    int end = start + 3125; if (end > NE) end = NE;
    for (int e = start + threadIdx.x; e < end; e += 256)
        atomicAdd(&hist[row[e] >> 8], 1);
    __syncthreads();
    for (int i = threadIdx.x; i < NBUCK; i += 256)
        hist[i] = atomicAdd(&gcursor[i], hist[i]);
    __syncthreads();
    for (int e = start + threadIdx.x; e < end; e += 256) {
        int r = row[e], c = col[e];
        int bk = r >> 8;
        int pos = atomicAdd(&hist[bk], 1);
        if (pos < CAP) ebuf[bk * CAP + pos] = (c << 8) | (r & 255);
    }
}

// ---- phase 2: per-bucket CSR build; bucket-scan folded in ----
__global__ __launch_bounds__(256) void k_build(const int* __restrict__ ebuf, const int* __restrict__ gcursor,
                                               int* __restrict__ row_ptr, float* __restrict__ dinv,
                                               float* __restrict__ rdeg, int* __restrict__ col_sorted) {
    __shared__ int deg[256], cur[256], ps[256];
    __shared__ int bsL[NBUCK + 1];
    int t = threadIdx.x;
    int d0 = (2 * t < NBUCK) ? gcursor[2 * t] : 0;
    int d1 = (2 * t + 1 < NBUCK) ? gcursor[2 * t + 1] : 0;
    ps[t] = d0 + d1;
    __syncthreads();
    for (int off = 1; off < 256; off <<= 1) {
        int v = (t >= off) ? ps[t - off] : 0;
        __syncthreads();
        ps[t] += v;
        __syncthreads();
    }
    int ex = ps[t] - d0 - d1;
    if (2 * t < NBUCK) bsL[2 * t] = ex;
    if (2 * t + 1 < NBUCK) bsL[2 * t + 1] = ex + d0;
    __syncthreads();
    int b = blockIdx.x;
    int bs = bsL[b];
    int cnt = gcursor[b];
    const int* eb = ebuf + (size_t)b * CAP;
    deg[t] = 0;
    __syncthreads();
    for (int e = t; e < cnt; e += 256)
        atomicAdd(&deg[eb[e] & 255], 1);
    __syncthreads();
    int d = deg[t];
    ps[t] = d; __syncthreads();
    for (int off = 1; off < 256; off <<= 1) {
        int v = (t >= off) ? ps[t - off] : 0;
        __syncthreads();
        ps[t] += v;
        __syncthreads();
    }
    int base = bs + ps[t] - d;
    cur[t] = base;
    int n = (b << 8) + t;
    if (n < NN) {
        row_ptr[n] = base;
        dinv[n] = d > 0 ? rsqrtf((float)d) : 0.f;
        rdeg[n] = sqrtf((float)d);
    }
    if (b == 0 && t == 0) row_ptr[NN] = NE;
    __syncthreads();
    for (int e = t; e < cnt; e += 256) {
        int w = eb[e];
        int pos = atomicAdd(&cur[w & 255], 1);
        col_sorted[pos] = ((unsigned)w) >> 8;
    }
}

// ---- bf16 copies: xbf = bf16(x), xsbf = bf16(x*dinv) ----
__global__ void k_scale(const float* __restrict__ x, const float* __restrict__ dinv,
                        unsigned short* __restrict__ xsbf, unsigned short* __restrict__ xbf) {
    int t = blockIdx.x * 256 + threadIdx.x;
    if (t < NN * 16) {
        float d = dinv[t >> 4];
        f32x4 v = ((const f32x4*)x)[t];
        bf16x4 u, s;
        u[0] = (short)f2bf(v[0]); u[1] = (short)f2bf(v[1]); u[2] = (short)f2bf(v[2]); u[3] = (short)f2bf(v[3]);
        s[0] = (short)f2bf(v[0] * d); s[1] = (short)f2bf(v[1] * d); s[2] = (short)f2bf(v[2] * d); s[3] = (short)f2bf(v[3] * d);
        ((bf16x4*)xbf)[t] = u;
        ((bf16x4*)xsbf)[t] = s;
    }
}

// ---- 64-wide bf16 SpMM. Pass1: outs only (T1s). Pass2: sub + outb only (T2). ----
__global__ __launch_bounds__(256) void k_spmm64b(const unsigned short* __restrict__ ins,
                                                 const unsigned short* __restrict__ subbf,
                                                 unsigned short* __restrict__ outb,
                                                 unsigned short* __restrict__ outsb,
                                                 const int* __restrict__ row_ptr, const int* __restrict__ cs,
                                                 const float* __restrict__ dinv,
                                                 int has_sub, int has_outb, int has_outs) {
    int n = blockIdx.x * 4 + (threadIdx.x >> 6);
    if (n >= NN) return;
    int nu = __builtin_amdgcn_readfirstlane(n);
    int lane = threadIdx.x & 63;
    int es = lane >> 3;     // edge slot 0..7
    int f = lane & 7;       // features 8f..8f+7 (16 B)
    int s = row_ptr[nu], e = row_ptr[nu + 1];
    float a0[8] = {0,0,0,0,0,0,0,0}, a1[8] = {0,0,0,0,0,0,0,0};
    int i = s;
    for (; i + 15 < e; i += 16) {
        int c0 = cs[i + es];
        int c1 = cs[i + 8 + es];
        bf16x8 v0 = *((const bf16x8*)(ins + (size_t)c0 * 64 + f * 8));
        bf16x8 v1 = *((const bf16x8*)(ins + (size_t)c1 * 64 + f * 8));
        #pragma unroll
        for (int j = 0; j < 8; ++j) { a0[j] += bf2f(v0[j]); a1[j] += bf2f(v1[j]); }
    }
    for (; i + es < e; i += 8) {            // masked remainder, <=2 iters
        int c0 = cs[i + es];
        bf16x8 v0 = *((const bf16x8*)(ins + (size_t)c0 * 64 + f * 8));
        #pragma unroll
        for (int j = 0; j < 8; ++j) a0[j] += bf2f(v0[j]);
    }
    float a[8];
    #pragma unroll
    for (int j = 0; j < 8; ++j) {
        a[j] = a0[j] + a1[j];
        a[j] += __shfl_xor(a[j], 8);
        a[j] += __shfl_xor(a[j], 16);
        a[j] += __shfl_xor(a[j], 32);
    }
    if (es == 0) {
        float dn = dinv[nu];
        float r[8];
        #pragma unroll
        for (int j = 0; j < 8; ++j) r[j] = -dn * a[j];
        if (has_sub) {
            bf16x8 sv = *((const bf16x8*)(subbf + (size_t)nu * 64 + f * 8));
            #pragma unroll
            for (int j = 0; j < 8; ++j) r[j] = 2.f * r[j] - bf2f(sv[j]);
        }
        if (has_outb) {
            bf16x8 ob;
            #pragma unroll
            for (int j = 0; j < 8; ++j) ob[j] = (short)f2bf(r[j]);
            *((bf16x8*)(outb + (size_t)nu * 64 + f * 8)) = ob;
        }
        if (has_outs) {
            bf16x8 os;
            #pragma unroll
            for (int j = 0; j < 8; ++j) os[j] = (short)f2bf(dn * r[j]);
            *((bf16x8*)(outsb + (size_t)nu * 64 + f * 8)) = os;
        }
    }
}

// ---- fused dense1 + proj via MFMA. T1 never materialized ----
__global__ __launch_bounds__(256) void k_d1p(const unsigned short* __restrict__ xbf,
                                             const unsigned short* __restrict__ t1s,
                                             const unsigned short* __restrict__ t2bf,
                                             const float* __restrict__ W1, const float* __restrict__ b1,
                                             const float* __restrict__ W2, const float* __restrict__ b2,
                                             const float* __restrict__ dinv, const float* __restrict__ rdeg,
                                             unsigned short* __restrict__ Apreb, unsigned short* __restrict__ Gsb) {
    __shared__ unsigned short Wf1[24 * 64 * 8];
    __shared__ unsigned short Wf2[6 * 64 * 8];
    __shared__ unsigned short Ht[4][1024];
    for (int slot = threadIdx.x; slot < 24 * 64; slot += 256) {
        int c = slot / 384;
        int t = (slot / 64) % 6;
        int l = slot & 63;
        int rr = l & 15, gg = l >> 4;
        unsigned int pk[4];
        #pragma unroll
        for (int jp = 0; jp < 4; ++jp) {
            int k0 = t * 32 + gg * 8 + jp * 2;
            unsigned int lo = f2bf(W1[(k0 >> 6) * 4096 + (k0 & 63) * 64 + c * 16 + rr]);
            int k1 = k0 + 1;
            unsigned int hi = f2bf(W1[(k1 >> 6) * 4096 + (k1 & 63) * 64 + c * 16 + rr]);
            pk[jp] = lo | (hi << 16);
        }
        *((uint4*)&Wf1[slot * 8]) = *((uint4*)pk);
    }
    for (int slot = threadIdx.x; slot < 6 * 64; slot += 256) {
        int c = slot / 128;
        int t = (slot / 64) & 1;
        int l = slot & 63;
        int rr = l & 15, gg = l >> 4;
        unsigned int pk[4];
        #pragma unroll
        for (int jp = 0; jp < 4; ++jp) {
            int k0 = t * 32 + gg * 8 + jp * 2;
            int k1 = k0 + 1;
            float w0, w1;
            if (c == 0)      { w0 = W2[k0 * 16 + rr] - W2[2048 + k0 * 16 + rr];
                               w1 = W2[k1 * 16 + rr] - W2[2048 + k1 * 16 + rr]; }
            else if (c == 1) { w0 = W2[1024 + k0 * 16 + rr]; w1 = W2[1024 + k1 * 16 + rr]; }
            else             { w0 = W2[2048 + k0 * 16 + rr]; w1 = W2[2048 + k1 * 16 + rr]; }
            pk[jp] = (unsigned int)f2bf(w0) | ((unsigned int)f2bf(w1) << 16);
        }
        *((uint4*)&Wf2[slot * 8]) = *((uint4*)pk);
    }
    __syncthreads();

    int lane = threadIdx.x & 63;
    int r = lane & 15, g = lane >> 4;
    int widx = threadIdx.x >> 6;
    char* ht = (char*)Ht[widx];

    bf16x8 bfr1[4][6];
    #pragma unroll
    for (int c = 0; c < 4; ++c)
        #pragma unroll
        for (int t = 0; t < 6; ++t)
            bfr1[c][t] = *((const bf16x8*)&Wf1[((c * 6 + t) * 64 + lane) * 8]);
    bf16x8 bfr2[3][2];
    #pragma unroll
    for (int c = 0; c < 3; ++c)
        #pragma unroll
        for (int t = 0; t < 2; ++t)
            bfr2[c][t] = *((const bf16x8*)&Wf2[((c * 2 + t) * 64 + lane) * 8]);

    float bl[4];
    #pragma unroll
    for (int c = 0; c < 4; ++c) bl[c] = b1[c * 16 + r];
    float b2r = b2[r];

    const unsigned short* arrs[3] = {xbf, t1s, t2bf};
    int wid = blockIdx.x * 4 + widx;
    int wstride = gridDim.x * 4;
    for (int tile = wid; tile < NN / 16; tile += wstride) {
        int nb = tile * 16;
        bf16x8 af[6];
        #pragma unroll
        for (int t = 0; t < 6; ++t)
            af[t] = *((const bf16x8*)(arrs[t >> 1] + (size_t)(nb + r) * 64 + (t & 1) * 32 + g * 8));
        f32x4 acc[4], accT[4];
        #pragma unroll
        for (int c = 0; c < 4; ++c) {
            acc[c] = (f32x4){bl[c], bl[c], bl[c], bl[c]};
            accT[c] = (f32x4){0.f, 0.f, 0.f, 0.f};
        }
        #pragma unroll
        for (int c = 0; c < 4; ++c) {
            acc[c]  = __builtin_amdgcn_mfma_f32_16x16x32_bf16(af[0], bfr1[c][0], acc[c], 0, 0, 0);
            acc[c]  = __builtin_amdgcn_mfma_f32_16x16x32_bf16(af[1], bfr1[c][1], acc[c], 0, 0, 0);
            accT[c] = __builtin_amdgcn_mfma_f32_16x16x32_bf16(af[2], bfr1[c][2], accT[c], 0, 0, 0);
            accT[c] = __builtin_amdgcn_mfma_f32_16x16x32_bf16(af[3], bfr1[c][3], accT[c], 0, 0, 0);
            acc[c]  = __builtin_amdgcn_mfma_f32_16x16x32_bf16(af[4], bfr1[c][4], acc[c], 0, 0, 0);
            acc[c]  = __builtin_amdgcn_mfma_f32_16x16x32_bf16(af[5], bfr1[c][5], acc[c], 0, 0, 0);
        }
        float rdq[4];
        #pragma unroll
        for (int q = 0; q < 4; ++q) rdq[q] = rdeg[nb + g * 4 + q];
        #pragma unroll
        for (int c = 0; c < 4; ++c)
            #pragma unroll
            for (int q = 0; q < 4; ++q) {
                float hval = fmaxf(acc[c][q] + rdq[q] * accT[c][q], 0.f);
                int node = g * 4 + q;
                int byte = (node * 64 + c * 16 + r) * 2;
                byte ^= (node & 7) << 4;
                *((unsigned short*)(ht + byte)) = f2bf(hval);
            }
        bf16x8 af2[2];
        #pragma unroll
        for (int t = 0; t < 2; ++t) {
            int byte = (r * 64 + t * 32 + g * 8) * 2;
            byte ^= (r & 7) << 4;
            af2[t] = *((const bf16x8*)(ht + byte));
        }
        f32x4 acc2[3];
        #pragma unroll
        for (int c = 0; c < 3; ++c) acc2[c] = (f32x4){0.f, 0.f, 0.f, 0.f};
        #pragma unroll
        for (int t = 0; t < 2; ++t)
            #pragma unroll
            for (int c = 0; c < 3; ++c)
                acc2[c] = __builtin_amdgcn_mfma_f32_16x16x32_bf16(af2[t], bfr2[c][t], acc2[c], 0, 0, 0);
        #pragma unroll
        for (int q = 0; q < 4; ++q) {
            int n = nb + g * 4 + q;
            float dv = dinv[n];
            Apreb[(size_t)n * 16 + r] = f2bf(acc2[0][q] + b2r);
            Gsb[(size_t)n * 32 + r]      = f2bf(acc2[1][q] * dv);
            Gsb[(size_t)n * 32 + 16 + r] = f2bf(acc2[2][q] * dv);
        }
    }
}

// ---- 32-wide bf16 SpMM: q1b = bf16(P(g1)); ts = bf16(dinv*P(g2)) ----
__global__ __launch_bounds__(256) void k_spmm32b(const unsigned short* __restrict__ Gsb,
                                                 unsigned short* __restrict__ q1b, unsigned short* __restrict__ tsb,
                                                 const int* __restrict__ row_ptr, const int* __restrict__ cs,
                                                 const float* __restrict__ dinv) {
    int n = blockIdx.x * 4 + (threadIdx.x >> 6);
    if (n >= NN) return;
    int nu = __builtin_amdgcn_readfirstlane(n);
    int lane = threadIdx.x & 63;
    int es = lane >> 3;
    int f = lane & 7;
    int s = row_ptr[nu], e = row_ptr[nu + 1];
    float a0[4] = {0,0,0,0}, a1[4] = {0,0,0,0};
    int i = s;
    for (; i + 15 < e; i += 16) {
        int c0 = cs[i + es];
        int c1 = cs[i + 8 + es];
        bf16x4 v0 = *((const bf16x4*)(Gsb + (size_t)c0 * 32 + f * 4));
        bf16x4 v1 = *((const bf16x4*)(Gsb + (size_t)c1 * 32 + f * 4));
        #pragma unroll
        for (int j = 0; j < 4; ++j) { a0[j] += bf2f(v0[j]); a1[j] += bf2f(v1[j]); }
    }
    for (; i + es < e; i += 8) {
        int c0 = cs[i + es];
        bf16x4 v0 = *((const bf16x4*)(Gsb + (size_t)c0 * 32 + f * 4));
        #pragma unroll
        for (int j = 0; j < 4; ++j) a0[j] += bf2f(v0[j]);
    }
    float a[4];
    #pragma unroll
    for (int j = 0; j < 4; ++j) {
        a[j] = a0[j] + a1[j];
        a[j] += __shfl_xor(a[j], 8);
        a[j] += __shfl_xor(a[j], 16);
        a[j] += __shfl_xor(a[j], 32);
    }
    if (es == 0) {
        float dn = dinv[nu];
        if (f < 4) {
            bf16x4 w;
            #pragma unroll
            for (int j = 0; j < 4; ++j) w[j] = (short)f2bf(-dn * a[j]);
            *((bf16x4*)(q1b + (size_t)nu * 16 + f * 4)) = w;
        } else {
            bf16x4 w;
            #pragma unroll
            for (int j = 0; j < 4; ++j) w[j] = (short)f2bf(dn * (-dn * a[j]));
            *((bf16x4*)(tsb + (size_t)nu * 16 + (f - 4) * 4)) = w;
        }
    }
}

// ---- 16-wide bf16 SpMM + combine + log_softmax ----
__global__ __launch_bounds__(256) void k_spmm16f(const unsigned short* __restrict__ tsb,
                                                 const unsigned short* __restrict__ Apreb,
                                                 const unsigned short* __restrict__ q1b,
                                                 const int* __restrict__ row_ptr, const int* __restrict__ cs,
                                                 const float* __restrict__ dinv, float* __restrict__ out) {
    int n = blockIdx.x * 4 + (threadIdx.x >> 6);
    if (n >= NN) return;
    int nu = __builtin_amdgcn_readfirstlane(n);
    int lane = threadIdx.x & 63;
    int es = lane >> 2;
    int f = lane & 3;
    int s = row_ptr[nu], e = row_ptr[nu + 1];
    float a0[4] = {0,0,0,0}, a1[4] = {0,0,0,0};
    int i = s;
    for (; i + 31 < e; i += 32) {
        int c0 = cs[i + es];
        int c1 = cs[i + 16 + es];
        bf16x4 v0 = *((const bf16x4*)(tsb + (size_t)c0 * 16 + f * 4));
        bf16x4 v1 = *((const bf16x4*)(tsb + (size_t)c1 * 16 + f * 4));
        #pragma unroll
        for (int j = 0; j < 4; ++j) { a0[j] += bf2f(v0[j]); a1[j] += bf2f(v1[j]); }
    }
    for (; i + es < e; i += 16) {
        int c0 = cs[i + es];
        bf16x4 v0 = *((const bf16x4*)(tsb + (size_t)c0 * 16 + f * 4));
        #pragma unroll
        for (int j = 0; j < 4; ++j) a0[j] += bf2f(v0[j]);
    }
    float a[4];
    #pragma unroll
    for (int j = 0; j < 4; ++j) {
        a[j] = a0[j] + a1[j];
        a[j] += __shfl_xor(a[j], 4);
        a[j] += __shfl_xor(a[j], 8);
        a[j] += __shfl_xor(a[j], 16);
        a[j] += __shfl_xor(a[j], 32);
    }
    if (es == 0) {
        float dn = dinv[nu];
        bf16x4 ap = *((const bf16x4*)(Apreb + (size_t)nu * 16 + f * 4));
        bf16x4 qv = *((const bf16x4*)(q1b + (size_t)nu * 16 + f * 4));
        float o[4];
        #pragma unroll
        for (int j = 0; j < 4; ++j)
            o[j] = bf2f(ap[j]) + bf2f(qv[j]) + 2.f * (-dn * a[j]);
        float m = fmaxf(fmaxf(o[0], o[1]), fmaxf(o[2], o[3]));
        m = fmaxf(m, __shfl_xor(m, 1));
        m = fmaxf(m, __shfl_xor(m, 2));
        float ssum = expf(o[0] - m) + expf(o[1] - m) + expf(o[2] - m) + expf(o[3] - m);
        ssum += __shfl_xor(ssum, 1);
        ssum += __shfl_xor(ssum, 2);
        float ls = logf(ssum);
        f32x4 w;
        w[0] = o[0] - m - ls; w[1] = o[1] - m - ls; w[2] = o[2] - m - ls; w[3] = o[3] - m - ls;
        *((f32x4*)(out + (size_t)nu * 16 + f * 4)) = w;
    }
}

extern "C" void kernel_launch(void* const* d_in, const int* in_sizes, int n_in,
                              void* d_out, int out_size, void* d_ws, size_t ws_size,
                              hipStream_t stream) {
    const float* x  = (const float*)d_in[0];
    const int*   ei = (const int*)d_in[1];
    const int*   row = ei;
    const int*   col = ei + NE;
    const float* W1 = (const float*)d_in[2];
    const float* b1 = (const float*)d_in[3];
    const float* W2 = (const float*)d_in[4];
    const float* b2 = (const float*)d_in[5];
    float* out = (float*)d_out;

    char* base = (char*)d_ws;
    size_t off = 0;
    auto alloc = [&](size_t bytes) -> char* {
        char* r = base + off;
        off = (off + bytes + 255) & ~(size_t)255;
        return r;
    };
    int*   gcursor    = (int*)alloc(NBUCK * 4);
    float* dinv       = (float*)alloc((size_t)NN * 4);
    float* rdeg       = (float*)alloc((size_t)NN * 4);
    int*   row_ptr    = (int*)alloc((size_t)(NN + 1) * 4);
    int*   ebuf       = (int*)alloc((size_t)NBUCK * CAP * 4);
    int*   col_sorted = (int*)alloc((size_t)NE * 4);
    unsigned short* Xbf  = (unsigned short*)alloc((size_t)NN * 64 * 2);
    unsigned short* XSbf = (unsigned short*)alloc((size_t)NN * 64 * 2);
    unsigned short* T1s  = (unsigned short*)alloc((size_t)NN * 64 * 2);
    unsigned short* T2bf = (unsigned short*)alloc((size_t)NN * 64 * 2);
    unsigned short* Apreb = (unsigned short*)alloc((size_t)NN * 16 * 2);
    unsigned short* Gsb  = (unsigned short*)alloc((size_t)NN * 32 * 2);
    unsigned short* q1b  = (unsigned short*)alloc((size_t)NN * 16 * 2);
    unsigned short* tsb  = (unsigned short*)alloc((size_t)NN * 16 * 2);

    hipMemsetAsync(gcursor, 0, NBUCK * 4, stream);

    // graph build (bstart folded into k_build)
    k_bin<<<512, 256, 0, stream>>>(row, col, gcursor, ebuf);
    k_build<<<NBUCK, 256, 0, stream>>>(ebuf, gcursor, row_ptr, dinv, rdeg, col_sorted);
    k_scale<<<(NN * 16 + 255) / 256, 256, 0, stream>>>(x, dinv, XSbf, Xbf);

    int nbS = (NN + 3) / 4;   // wave per node
    // layer 1 propagations: pass1 -> T1s only; pass2 -> T2 only
    k_spmm64b<<<nbS, 256, 0, stream>>>(XSbf, nullptr, nullptr, T1s, row_ptr, col_sorted, dinv, 0, 0, 1);
    k_spmm64b<<<nbS, 256, 0, stream>>>(T1s, Xbf, T2bf, nullptr, row_ptr, col_sorted, dinv, 1, 1, 0);
    // fused dense1 + layer-2 projection (h on-chip; T1 reconstructed via rdeg)
    k_d1p<<<625, 256, 0, stream>>>(Xbf, T1s, T2bf, W1, b1, W2, b2, dinv, rdeg, Apreb, Gsb);
    // layer-2 narrow propagations
    k_spmm32b<<<nbS, 256, 0, stream>>>(Gsb, q1b, tsb, row_ptr, col_sorted, dinv);
    k_spmm16f<<<nbS, 256, 0, stream>>>(tsb, Apreb, q1b, row_ptr, col_sorted, dinv, out);
}